// Round 3
// baseline (855.210 us; speedup 1.0000x reference)
//
#include <hip/hip_runtime.h>
#include <hip/hip_bf16.h>
#include <cstdint>
#include <cstddef>

typedef unsigned short u16;
typedef __attribute__((ext_vector_type(8))) short s8v;   // 8 x bf16 (4 VGPRs) MFMA A/B frag
typedef __attribute__((ext_vector_type(4))) float f4v;   // MFMA C/D frag

__device__ __forceinline__ float bf2f(u16 u) {
  union { unsigned u; float f; } v; v.u = ((unsigned)u) << 16; return v.f;
}
// native HW convert (RNE via v_cvt); m240: do NOT hand-write cvt_pk
__device__ __forceinline__ u16 f2bf(float f) {
  __hip_bfloat16 h = __float2bfloat16(f);
  return *reinterpret_cast<u16*>(&h);
}

// async global->LDS, 16B per lane. LDS dest must be wave-uniform base; HW adds lane*16.
__device__ __forceinline__ void async16(u16* lds, const u16* g) {
  __builtin_amdgcn_global_load_lds((const __attribute__((address_space(1))) void*)g,
                                   (__attribute__((address_space(3))) void*)lds,
                                   16, 0, 0);
}

// ---------------- elementwise f32 -> bf16 ----------------
__global__ __launch_bounds__(256) void k_f32_to_bf16(const float* __restrict__ in,
                                                     u16* __restrict__ out, int n8) {
  int i = blockIdx.x * 256 + threadIdx.x;
  if (i >= n8) return;
  const float4* p = (const float4*)(in + (size_t)i * 8);
  float4 a = p[0], b = p[1];
  s8v ov;
  ov[0] = (short)f2bf(a.x); ov[1] = (short)f2bf(a.y);
  ov[2] = (short)f2bf(a.z); ov[3] = (short)f2bf(a.w);
  ov[4] = (short)f2bf(b.x); ov[5] = (short)f2bf(b.y);
  ov[6] = (short)f2bf(b.z); ov[7] = (short)f2bf(b.w);
  *(s8v*)(out + (size_t)i * 8) = ov;
}

// ---------------- W (K,N) f32 -> Wt (N,K) bf16 ----------------
__global__ __launch_bounds__(256) void k_transpose_bf16(const float* __restrict__ W,
                                                        u16* __restrict__ Wt, int K, int N) {
  __shared__ float tile[32][33];
  int n0 = blockIdx.x * 32, k0 = blockIdx.y * 32;
  int tx = threadIdx.x & 31, ty = threadIdx.x >> 5;  // ty 0..7
#pragma unroll
  for (int i = 0; i < 32; i += 8)
    tile[ty + i][tx] = W[(size_t)(k0 + ty + i) * N + n0 + tx];
  __syncthreads();
#pragma unroll
  for (int i = 0; i < 32; i += 8)
    Wt[(size_t)(n0 + ty + i) * K + k0 + tx] = f2bf(tile[tx][ty + i]);
}

// ---------------- GEMM: C = A(M,K) * Bt(N,K)^T, bf16 in, fused epilogues ----------
// EPI: 0 = plain bf16 (ldc=N, C0)          1 = f32 (ldc=N, C0)
//      2 = DQKV: col<split -> q_c(1536), else kv_c(512)
//      3 = UQQR: col<split -> qbuf remap(3072/192), else qr_raw(1024)
//      4 = UKUV: col<split -> kbuf remap(3072/192), else vtmp(2048)
// Split points are multiples of BN => branch is block-uniform.
template <int BM, int BN, int WVM, int WVN, int EPI>
__global__ __launch_bounds__(256, 2) void k_gemm(const u16* __restrict__ A,
                                                 const u16* __restrict__ Bt,
                                                 void* __restrict__ C0v,
                                                 void* __restrict__ C1v,
                                                 int M, int N, int K, int split) {
  constexpr int FM = BM / WVM / 16, FN = BN / WVN / 16;
  __shared__ __align__(16) u16 As[BM * 32];
  __shared__ __align__(16) u16 Bs[BN * 32];
  const int tid = threadIdx.x, wv = tid >> 6, ln = tid & 63;
  const int lo = ln & 15, hi = ln >> 4;
  const int wr = wv / WVN, wc = wv % WVN;

  int nwg = gridDim.x, bid = blockIdx.x;
  int s = (bid & 7) * (nwg >> 3) + (bid >> 3);  // XCD swizzle (nwg % 8 == 0 everywhere)
  int gm = M / BM;
  int m0 = (s % gm) * BM, n0 = (s / gm) * BN;

  f4v acc[FM][FN] = {};

  for (int k0 = 0; k0 < K; k0 += 32) {
    __syncthreads();
#pragma unroll
    for (int i = 0; i < BM / 64; i++) {
      int r = i * 64 + wv * 16 + (ln >> 2);
      async16(&As[(i * 64 + wv * 16) * 32],
              A + (size_t)(m0 + r) * K + k0 + (ln & 3) * 8);
    }
#pragma unroll
    for (int i = 0; i < BN / 64; i++) {
      int r = i * 64 + wv * 16 + (ln >> 2);
      async16(&Bs[(i * 64 + wv * 16) * 32],
              Bt + (size_t)(n0 + r) * K + k0 + (ln & 3) * 8);
    }
    __syncthreads();  // drains vmcnt(0): staged data visible

    s8v af[FM], bf[FN];
#pragma unroll
    for (int m = 0; m < FM; m++)
      af[m] = *(const s8v*)&As[(wr * FM * 16 + m * 16 + lo) * 32 + hi * 8];
#pragma unroll
    for (int n = 0; n < FN; n++)
      bf[n] = *(const s8v*)&Bs[(wc * FN * 16 + n * 16 + lo) * 32 + hi * 8];
#pragma unroll
    for (int m = 0; m < FM; m++)
#pragma unroll
      for (int n = 0; n < FN; n++)
        acc[m][n] = __builtin_amdgcn_mfma_f32_16x16x32_bf16(af[m], bf[n], acc[m][n], 0, 0, 0);
  }

  bool second = (n0 >= split);  // block-uniform
#pragma unroll
  for (int m = 0; m < FM; m++)
#pragma unroll
    for (int n = 0; n < FN; n++)
#pragma unroll
      for (int j = 0; j < 4; j++) {
        int row = m0 + wr * FM * 16 + m * 16 + hi * 4 + j;
        int col = n0 + wc * FN * 16 + n * 16 + lo;
        float v = acc[m][n][j];
        if constexpr (EPI == 0) {
          ((u16*)C0v)[(size_t)row * N + col] = f2bf(v);
        } else if constexpr (EPI == 1) {
          ((float*)C0v)[(size_t)row * N + col] = v;
        } else if constexpr (EPI == 2) {
          if (second) ((u16*)C1v)[(size_t)row * 512 + (col - 1536)] = f2bf(v);
          else        ((u16*)C0v)[(size_t)row * 1536 + col] = f2bf(v);
        } else if constexpr (EPI == 3) {
          if (second) ((u16*)C1v)[(size_t)row * 1024 + (col - 2048)] = f2bf(v);
          else        ((u16*)C0v)[(size_t)row * 3072 + (col >> 7) * 192 + (col & 127)] = f2bf(v);
        } else {  // EPI == 4
          if (second) ((u16*)C1v)[(size_t)row * 2048 + (col - 2048)] = f2bf(v);
          else        ((u16*)C0v)[(size_t)row * 3072 + (col >> 7) * 192 + (col & 127)] = f2bf(v);
        }
      }
}

// ---------------- in-place RMSNorm over rows of bf16 (block = C/8 threads) ----------
__global__ void k_rmsnorm(u16* __restrict__ buf, const float* __restrict__ g, int C) {
  int row = blockIdx.x;
  u16* p = buf + (size_t)row * C;
  int tid = threadIdx.x;
  float x[8];
  float ss = 0.f;
  s8v v = *(const s8v*)(p + tid * 8);
#pragma unroll
  for (int i = 0; i < 8; i++) { float xi = bf2f((u16)v[i]); x[i] = xi; ss += xi * xi; }
#pragma unroll
  for (int off = 1; off < 64; off <<= 1) ss += __shfl_xor(ss, off);
  __shared__ float red[4];
  if (tid < 4) red[tid] = 0.f;
  __syncthreads();
  if ((tid & 63) == 0) red[tid >> 6] = ss;
  __syncthreads();
  float sc = rsqrtf((red[0] + red[1] + red[2] + red[3]) / (float)C + 1e-6f);
  s8v ov;
#pragma unroll
  for (int i = 0; i < 8; i++) ov[i] = (short)f2bf(x[i] * sc * g[tid * 8 + i]);
  *(s8v*)(p + tid * 8) = ov;
}

// ---------------- RoPE on q_rope, scatter into qbuf[:, h*192+128 ..] ----------------
__global__ __launch_bounds__(256) void k_rope_q(const u16* __restrict__ qr,
                                                const float* __restrict__ freqs,
                                                u16* __restrict__ qbuf) {
  int idx = blockIdx.x * 256 + threadIdx.x;  // (r,h)
  int r = idx >> 4, h = idx & 15;
  int t = r & 2047;
  const u16* src = qr + (size_t)r * 1024 + h * 64;
  u16* dst = qbuf + (size_t)r * 3072 + h * 192 + 128;
  const float* fc = freqs + (size_t)t * 64;
  u16 in[64], out[64];
#pragma unroll
  for (int c = 0; c < 8; c++) {
    s8v vv = *(const s8v*)(src + c * 8);
#pragma unroll
    for (int e = 0; e < 8; e++) in[c * 8 + e] = (u16)vv[e];
  }
#pragma unroll
  for (int i = 0; i < 32; i++) {
    float x1 = bf2f(in[2 * i]), x2 = bf2f(in[2 * i + 1]);
    float co = fc[2 * i], si = fc[2 * i + 1];
    out[2 * i] = f2bf(x1 * co - x2 * si);
    out[2 * i + 1] = f2bf(x1 * si + x2 * co);
  }
#pragma unroll
  for (int c = 0; c < 8; c++) {
    s8v ov;
#pragma unroll
    for (int e = 0; e < 8; e++) ov[e] = (short)out[c * 8 + e];
    *(s8v*)(dst + c * 8) = ov;
  }
}

// ---------------- RoPE on k_rope (shared across heads), broadcast into kbuf ----------
__global__ __launch_bounds__(256) void k_rope_k(const u16* __restrict__ kr,
                                                const float* __restrict__ freqs,
                                                u16* __restrict__ kbuf) {
  int idx = blockIdx.x * 256 + threadIdx.x;  // (r,h)
  int r = idx >> 4, h = idx & 15;
  int t = r & 2047;
  const u16* src = kr + (size_t)r * 64;
  u16* dst = kbuf + (size_t)r * 3072 + h * 192 + 128;
  const float* fc = freqs + (size_t)t * 64;
  u16 in[64], out[64];
#pragma unroll
  for (int c = 0; c < 8; c++) {
    s8v vv = *(const s8v*)(src + c * 8);
#pragma unroll
    for (int e = 0; e < 8; e++) in[c * 8 + e] = (u16)vv[e];
  }
#pragma unroll
  for (int i = 0; i < 32; i++) {
    float x1 = bf2f(in[2 * i]), x2 = bf2f(in[2 * i + 1]);
    float co = fc[2 * i], si = fc[2 * i + 1];
    out[2 * i] = f2bf(x1 * co - x2 * si);
    out[2 * i + 1] = f2bf(x1 * si + x2 * co);
  }
#pragma unroll
  for (int c = 0; c < 8; c++) {
    s8v ov;
#pragma unroll
    for (int e = 0; e < 8; e++) ov[e] = (short)out[c * 8 + e];
    *(s8v*)(dst + c * 8) = ov;
  }
}

// ---------------- V (token, h*128+d) -> Vt (B,H,128,T) ----------------
__global__ __launch_bounds__(256) void k_transpose_v(const u16* __restrict__ vtmp,
                                                     u16* __restrict__ vt) {
  __shared__ __align__(16) u16 tile[64][72];
  int r0 = blockIdx.x * 64, c0 = blockIdx.y * 64;
  int b = r0 >> 11, t0 = r0 & 2047;
  int h = c0 >> 7, d0 = c0 & 127;
  int tid = threadIdx.x;
  int ci = (tid & 7) * 8, ri = tid >> 3;  // ri 0..31
#pragma unroll
  for (int i = 0; i < 2; i++)
    *(s8v*)&tile[ri + 32 * i][ci] =
        *(const s8v*)(vtmp + (size_t)(r0 + ri + 32 * i) * 2048 + c0 + ci);
  __syncthreads();
  int tx = tid & 7, rr = tid >> 3;
#pragma unroll
  for (int i = 0; i < 2; i++) {
    int dr = rr + 32 * i;
    s8v ov;
#pragma unroll
    for (int e = 0; e < 8; e++) ov[e] = (short)tile[tx * 8 + e][dr];
    *(s8v*)(vt + (size_t)((b * 16 + h) * 128 + d0 + dr) * 2048 + t0 + tx * 8) = ov;
  }
}

// ---------------- causal flash attention, LDS-staged K/V ----------------
// Softmax discipline: scale folded into exp2 arg; T13 defer-max (THR=8 in scaled
// units) skips max-reduce + O/l rescale on nearly every tile; l kept as per-lane
// partials, reduced once after the loop.
__global__ __launch_bounds__(256, 3) void k_attn(const u16* __restrict__ Q,
                                                 const u16* __restrict__ K,
                                                 const u16* __restrict__ V,
                                                 u16* __restrict__ O) {
  __shared__ __align__(16) u16 Ks[64 * 192];      // 24.6 KB
  __shared__ __align__(16) u16 Vs[128 * 64];      // 16.4 KB
  __shared__ __align__(16) u16 p_lds[4][16 * 88]; // 11.3 KB
  int bid = blockIdx.x;
  // XCD-chunked remap (2048 = 8 XCD x 256) + long-tiles-first for causal balance
  int lw = (bid & 7) * 256 + (bid >> 3);
  int qt = 31 - (lw & 31), h = (lw >> 5) & 15, b = lw >> 9;
  int tid = threadIdx.x, wv = tid >> 6, ln = tid & 63;
  int lo = ln & 15, hi = ln >> 4, lo7 = lo & 7;
  int qb = qt * 64 + wv * 16;

  const u16* qptr = Q + (size_t)(b * 2048 + qb + lo) * 3072 + h * 192 + hi * 8;
  s8v qf[6];
#pragma unroll
  for (int ks = 0; ks < 6; ks++) qf[ks] = *(const s8v*)(qptr + ks * 32);

  f4v Oa[8] = {};
  float m_r[4], lpart[4];
#pragma unroll
  for (int j = 0; j < 4; j++) { m_r[j] = -3e38f; lpart[j] = 0.f; }
  const float sl2 = 0.07216878364870323f * 1.44269504f;  // scale * log2(e)
  const float THRU = 11.5f / sl2;  // defer-max threshold (P bounded by 2^11.5 ~ e^8)

  const u16* kg = K + (size_t)(b * 2048) * 3072 + h * 192;
  const u16* vg = V + (size_t)((b * 16 + h) * 128) * 2048;
  int kgo[6], klo[6];  // K: 64 rows x 24 chunks(16B) / 256 thr = 6
#pragma unroll
  for (int i = 0; i < 6; i++) {
    int id = i * 256 + tid, r = id / 24, c = id % 24;
    kgo[i] = r * 3072 + c * 8;
    klo[i] = r * 192 + (c ^ (r & 7)) * 8;
  }
  int vgo[4], vlo[4];  // V: 128 rows x 8 chunks / 256 thr = 4
#pragma unroll
  for (int i = 0; i < 4; i++) {
    int id = i * 256 + tid, r = id >> 3, c = id & 7;
    vgo[i] = r * 2048 + c * 8;
    vlo[i] = r * 64 + (c ^ (r & 7)) * 8;
  }

  u16* pl = p_lds[wv];
  int last = (qb + 15) >> 6;
  s8v kreg[6], vreg[4];

  // prologue: stage tile 0
#pragma unroll
  for (int i = 0; i < 6; i++) kreg[i] = *(const s8v*)(kg + kgo[i]);
#pragma unroll
  for (int i = 0; i < 4; i++) vreg[i] = *(const s8v*)(vg + vgo[i]);
#pragma unroll
  for (int i = 0; i < 6; i++) *(s8v*)&Ks[klo[i]] = kreg[i];
#pragma unroll
  for (int i = 0; i < 4; i++) *(s8v*)&Vs[vlo[i]] = vreg[i];
  __syncthreads();

  for (int t = 0; t <= last; t++) {
    int kv0 = t * 64;
    // T14: issue next tile's global loads; latency hides under compute
    if (t < last) {
      size_t ksh = (size_t)(kv0 + 64) * 3072;
#pragma unroll
      for (int i = 0; i < 6; i++) kreg[i] = *(const s8v*)(kg + ksh + kgo[i]);
#pragma unroll
      for (int i = 0; i < 4; i++) vreg[i] = *(const s8v*)(vg + (kv0 + 64) + vgo[i]);
    }

    // ---- QK^T from swizzled LDS ----
    f4v S[4] = {};
    __builtin_amdgcn_s_setprio(1);
#pragma unroll
    for (int ks = 0; ks < 6; ks++)
#pragma unroll
      for (int nf = 0; nf < 4; nf++) {
        s8v kf = *(const s8v*)&Ks[(nf * 16 + lo) * 192 + (((ks * 4 + hi) ^ lo7) * 8)];
        S[nf] = __builtin_amdgcn_mfma_f32_16x16x32_bf16(qf[ks], kf, S[nf], 0, 0, 0);
      }
    __builtin_amdgcn_s_setprio(0);

    // ---- online softmax (unscaled scores; scale folded into exp2) ----
    float p[4][4], tmax[4];
#pragma unroll
    for (int j = 0; j < 4; j++) tmax[j] = -3e38f;
    if (t == last) {
#pragma unroll
      for (int nf = 0; nf < 4; nf++)
#pragma unroll
        for (int j = 0; j < 4; j++) {
          float sv = S[nf][j];
          if (kv0 + nf * 16 + lo > qb + hi * 4 + j) sv = -3e38f;
          p[nf][j] = sv;
          tmax[j] = fmaxf(tmax[j], sv);
        }
    } else {
#pragma unroll
      for (int nf = 0; nf < 4; nf++)
#pragma unroll
        for (int j = 0; j < 4; j++) {
          p[nf][j] = S[nf][j];
          tmax[j] = fmaxf(tmax[j], S[nf][j]);
        }
    }
    bool need = false;
#pragma unroll
    for (int j = 0; j < 4; j++) need = need || (tmax[j] > m_r[j] + THRU);
    if (__any(need)) {  // rescale path (rare after tile 0)
#pragma unroll
      for (int off = 1; off < 16; off <<= 1)
#pragma unroll
        for (int j = 0; j < 4; j++) tmax[j] = fmaxf(tmax[j], __shfl_xor(tmax[j], off));
#pragma unroll
      for (int j = 0; j < 4; j++) {
        float nm = fmaxf(m_r[j], tmax[j]);
        float fj = exp2f((m_r[j] - nm) * sl2);
        m_r[j] = nm;
        lpart[j] *= fj;
#pragma unroll
        for (int df = 0; df < 8; df++) Oa[df][j] *= fj;
      }
    }
#pragma unroll
    for (int nf = 0; nf < 4; nf++)
#pragma unroll
      for (int j = 0; j < 4; j++) {
        float pv = exp2f((p[nf][j] - m_r[j]) * sl2);
        p[nf][j] = pv;
        lpart[j] += pv;
      }

    // P (C-layout) -> per-wave LDS -> A-fragment layout
#pragma unroll
    for (int nf = 0; nf < 4; nf++)
#pragma unroll
      for (int j = 0; j < 4; j++)
        pl[(hi * 4 + j) * 88 + nf * 16 + lo] = f2bf(p[nf][j]);

    // ---- PV from swizzled LDS ----
    __builtin_amdgcn_s_setprio(1);
#pragma unroll
    for (int ks2 = 0; ks2 < 2; ks2++) {
      s8v pa = *(const s8v*)&pl[lo * 88 + ks2 * 32 + hi * 8];
#pragma unroll
      for (int df = 0; df < 8; df++) {
        s8v vf = *(const s8v*)&Vs[(df * 16 + lo) * 64 + (((ks2 * 4 + hi) ^ lo7) * 8)];
        Oa[df] = __builtin_amdgcn_mfma_f32_16x16x32_bf16(pa, vf, Oa[df], 0, 0, 0);
      }
    }
    __builtin_amdgcn_s_setprio(0);

    __syncthreads();  // all waves done reading tile t
    if (t < last) {
#pragma unroll
      for (int i = 0; i < 6; i++) *(s8v*)&Ks[klo[i]] = kreg[i];
#pragma unroll
      for (int i = 0; i < 4; i++) *(s8v*)&Vs[vlo[i]] = vreg[i];
      __syncthreads();  // tile t+1 visible
    }
  }

  // deferred l reduction (once, not per tile)
#pragma unroll
  for (int off = 1; off < 16; off <<= 1)
#pragma unroll
    for (int j = 0; j < 4; j++) lpart[j] += __shfl_xor(lpart[j], off);

#pragma unroll
  for (int j = 0; j < 4; j++) {
    float inv = 1.0f / lpart[j];
    u16* orow = O + (size_t)(b * 2048 + qb + hi * 4 + j) * 2048 + h * 128;
#pragma unroll
    for (int df = 0; df < 8; df++) orow[df * 16 + lo] = f2bf(Oa[df][j] * inv);
  }
}

// =====================================================================
extern "C" void kernel_launch(void* const* d_in, const int* in_sizes, int n_in,
                              void* d_out, int out_size, void* d_ws, size_t ws_size,
                              hipStream_t stream) {
  (void)in_sizes; (void)n_in; (void)out_size; (void)ws_size;
  const float* x     = (const float*)d_in[0];
  const float* freqs = (const float*)d_in[2];
  const float* W_dq  = (const float*)d_in[4];
  const float* W_uq  = (const float*)d_in[5];
  const float* W_dkv = (const float*)d_in[6];
  const float* W_uk  = (const float*)d_in[7];
  const float* W_uv  = (const float*)d_in[8];
  const float* W_qr  = (const float*)d_in[9];
  const float* W_kr  = (const float*)d_in[10];
  const float* W_o   = (const float*)d_in[11];
  const float* g_q   = (const float*)d_in[12];
  const float* g_kv  = (const float*)d_in[13];
  float* out = (float*)d_out;

  const int M = 8192;  // B*T
  char* w = (char*)d_ws;
  auto alloc = [&](size_t n) { char* p = w; w += (n + 255) & ~(size_t)255; return p; };

  u16* xb     = (u16*)alloc((size_t)M * 2048 * 2);  // reused as vtmp and aout
  // fused-B pairs MUST stay contiguous (sizes are 256B-multiples):
  u16* wdq    = (u16*)alloc((size_t)1536 * 2048 * 2);
  u16* wdkv   = (u16*)alloc((size_t)512 * 2048 * 2);   // = wdq + 1536*2048
  u16* wuq    = (u16*)alloc((size_t)2048 * 1536 * 2);
  u16* wqr    = (u16*)alloc((size_t)1024 * 1536 * 2);  // = wuq + 2048*1536
  u16* wuk    = (u16*)alloc((size_t)2048 * 512 * 2);
  u16* wuv    = (u16*)alloc((size_t)2048 * 512 * 2);   // = wuk + 2048*512
  u16* wkr    = (u16*)alloc((size_t)64 * 2048 * 2);
  u16* wo     = (u16*)alloc((size_t)2048 * 2048 * 2);
  u16* q_c    = (u16*)alloc((size_t)M * 1536 * 2);
  u16* kv_c   = (u16*)alloc((size_t)M * 512 * 2);
  u16* qr_raw = (u16*)alloc((size_t)M * 1024 * 2);
  u16* kr_raw = (u16*)alloc((size_t)M * 64 * 2);
  u16* qbuf   = (u16*)alloc((size_t)M * 3072 * 2);
  u16* kbuf   = (u16*)alloc((size_t)M * 3072 * 2);
  u16* vt     = (u16*)alloc((size_t)M * 2048 * 2);
  u16* vtmp = xb;  // xb dead after kr GEMM
  u16* aout = xb;

  // ---- preamble: bf16 conversion + weight transposes ----
  k_f32_to_bf16<<<M * 2048 / 8 / 256, 256, 0, stream>>>(x, xb, M * 2048 / 8);
  k_transpose_bf16<<<dim3(1536 / 32, 2048 / 32), 256, 0, stream>>>(W_dq, wdq, 2048, 1536);
  k_transpose_bf16<<<dim3(512 / 32, 2048 / 32), 256, 0, stream>>>(W_dkv, wdkv, 2048, 512);
  k_transpose_bf16<<<dim3(2048 / 32, 1536 / 32), 256, 0, stream>>>(W_uq, wuq, 1536, 2048);
  k_transpose_bf16<<<dim3(1024 / 32, 1536 / 32), 256, 0, stream>>>(W_qr, wqr, 1536, 1024);
  k_transpose_bf16<<<dim3(2048 / 32, 512 / 32), 256, 0, stream>>>(W_uk, wuk, 512, 2048);
  k_transpose_bf16<<<dim3(2048 / 32, 512 / 32), 256, 0, stream>>>(W_uv, wuv, 512, 2048);
  k_transpose_bf16<<<dim3(64 / 32, 2048 / 32), 256, 0, stream>>>(W_kr, wkr, 2048, 64);
  k_transpose_bf16<<<dim3(2048 / 32, 2048 / 32), 256, 0, stream>>>(W_o, wo, 2048, 2048);

  // ---- fused latent projections (dq|dkv) + RMSNorm ----
  k_gemm<128, 128, 2, 2, 2><<<(M / 128) * (2048 / 128), 256, 0, stream>>>(
      xb, wdq, q_c, kv_c, M, 2048, 2048, 1536);
  k_rmsnorm<<<M, 192, 0, stream>>>(q_c, g_q, 1536);
  k_rmsnorm<<<M, 64, 0, stream>>>(kv_c, g_kv, 512);

  // ---- fused Q up-projections (uq|qr) + rope ----
  k_gemm<128, 128, 2, 2, 3><<<(M / 128) * (3072 / 128), 256, 0, stream>>>(
      q_c, wuq, qbuf, qr_raw, M, 3072, 1536, 2048);
  k_rope_q<<<M * 16 / 256, 256, 0, stream>>>(qr_raw, freqs, qbuf);

  // ---- K rope path (reads xb -> must precede ukuv which writes vtmp=xb) ----
  k_gemm<128, 64, 4, 1, 0><<<(M / 128) * (64 / 64), 256, 0, stream>>>(
      xb, wkr, kr_raw, nullptr, M, 64, 2048, 1 << 30);
  k_rope_k<<<M * 16 / 256, 256, 0, stream>>>(kr_raw, freqs, kbuf);

  // ---- fused KV up-projections (uk|uv) + V transpose ----
  k_gemm<128, 128, 2, 2, 4><<<(M / 128) * (4096 / 128), 256, 0, stream>>>(
      kv_c, wuk, kbuf, vtmp, M, 4096, 512, 2048);
  k_transpose_v<<<dim3(M / 64, 2048 / 64), 256, 0, stream>>>(vtmp, vt);

  // ---- attention ----
  k_attn<<<4 * 16 * 32, 256, 0, stream>>>(qbuf, kbuf, vt, aout);

  // ---- output projection (f32 out) ----
  k_gemm<128, 128, 2, 2, 1><<<(M / 128) * (2048 / 128), 256, 0, stream>>>(
      aout, wo, out, nullptr, M, 2048, 2048, 1 << 30);
}

// Round 5
// 791.245 us; speedup vs baseline: 1.0808x; 1.0808x over previous
//
#include <hip/hip_runtime.h>
#include <hip/hip_bf16.h>
#include <cstdint>
#include <cstddef>

typedef unsigned short u16;
typedef __attribute__((ext_vector_type(8))) short s8v;   // 8 x bf16 (4 VGPRs) MFMA A/B frag
typedef __attribute__((ext_vector_type(4))) float f4v;   // MFMA C/D frag

__device__ __forceinline__ float bf2f(u16 u) {
  union { unsigned u; float f; } v; v.u = ((unsigned)u) << 16; return v.f;
}
__device__ __forceinline__ u16 f2bf(float f) {
  __hip_bfloat16 h = __float2bfloat16(f);
  return *reinterpret_cast<u16*>(&h);
}

// async global->LDS, 16B per lane. LDS dest must be wave-uniform base; HW adds lane*16.
__device__ __forceinline__ void async16(u16* lds, const u16* g) {
  __builtin_amdgcn_global_load_lds((const __attribute__((address_space(1))) void*)g,
                                   (__attribute__((address_space(3))) void*)lds,
                                   16, 0, 0);
}

// ---------------- elementwise f32 -> bf16 ----------------
__global__ __launch_bounds__(256) void k_f32_to_bf16(const float* __restrict__ in,
                                                     u16* __restrict__ out, int n8) {
  int i = blockIdx.x * 256 + threadIdx.x;
  if (i >= n8) return;
  const float4* p = (const float4*)(in + (size_t)i * 8);
  float4 a = p[0], b = p[1];
  s8v ov;
  ov[0] = (short)f2bf(a.x); ov[1] = (short)f2bf(a.y);
  ov[2] = (short)f2bf(a.z); ov[3] = (short)f2bf(a.w);
  ov[4] = (short)f2bf(b.x); ov[5] = (short)f2bf(b.y);
  ov[6] = (short)f2bf(b.z); ov[7] = (short)f2bf(b.w);
  *(s8v*)(out + (size_t)i * 8) = ov;
}

// ---------------- ALL weight transposes (K,N)f32 -> (N,K)bf16, one launch --------
__global__ __launch_bounds__(256) void k_transpose_all(
    const float* w0, const float* w1, const float* w2, const float* w3,
    const float* w4, const float* w5, const float* w6, const float* w7,
    u16* t0, u16* t1, u16* t2, u16* t3, u16* t4, u16* t5, u16* t6, u16* t7) {
  int bid = blockIdx.x;
  const float* W; u16* Wt; int K, N, lb;
  if (bid < 3072)       { W = w0; Wt = t0; K = 2048; N = 1536; lb = bid; }
  else if (bid < 4096)  { W = w1; Wt = t1; K = 2048; N = 512;  lb = bid - 3072; }
  else if (bid < 7168)  { W = w2; Wt = t2; K = 1536; N = 2048; lb = bid - 4096; }
  else if (bid < 8704)  { W = w3; Wt = t3; K = 1536; N = 1024; lb = bid - 7168; }
  else if (bid < 9728)  { W = w4; Wt = t4; K = 512;  N = 2048; lb = bid - 8704; }
  else if (bid < 10752) { W = w5; Wt = t5; K = 512;  N = 2048; lb = bid - 9728; }
  else if (bid < 10880) { W = w6; Wt = t6; K = 2048; N = 64;   lb = bid - 10752; }
  else                  { W = w7; Wt = t7; K = 2048; N = 2048; lb = bid - 10880; }
  int nb = N >> 5;
  int n0 = (lb % nb) * 32, k0 = (lb / nb) * 32;
  __shared__ float tile[32][33];
  int tx = threadIdx.x & 31, ty = threadIdx.x >> 5;
#pragma unroll
  for (int i = 0; i < 32; i += 8)
    tile[ty + i][tx] = W[(size_t)(k0 + ty + i) * N + n0 + tx];
  __syncthreads();
#pragma unroll
  for (int i = 0; i < 32; i += 8)
    Wt[(size_t)(n0 + ty + i) * K + k0 + tx] = f2bf(tile[tx][ty + i]);
}

// =====================================================================
// 256x256 8-phase GEMM (T2 swizzle + T3/T4 counted vmcnt + T5 setprio)
// C = A(M,K) * Bt(N,K)^T. 512 threads = 8 waves (2M x 4N), BK=64, 128 KiB LDS.
// EPI: 1 = f32 (ldc=N)   2 = DQKV split->q_c/kv_c   3 = UQQR   4 = UKUV
// Stage stream per K-tile kt: P1:A1(kt+1) P2:B0(kt+2) P3:B1(kt+2) P4:A0(kt+2),
// vmcnt(6) checkpoint at P4 (=> kt+1 fully staged; region last-read phases
// strictly precede overwrite-issue phases -- see deadline analysis).
// =====================================================================
template <int EPI>
__global__ __launch_bounds__(512, 2) void k_gemm8(const u16* __restrict__ A,
                                                  const u16* __restrict__ Bt,
                                                  void* __restrict__ C0v,
                                                  void* __restrict__ C1v,
                                                  int M, int N, int K, int split) {
  // LDS regions (u16 elems): ((dbuf*2 + mat)*2 + half)*8192, mat 0=A 1=B
  __shared__ __align__(16) u16 lds[65536];  // 128 KiB
  const int tid = threadIdx.x, wv = tid >> 6, ln = tid & 63;
  const int lo = ln & 15, hi = ln >> 4;
  const int wm = wv >> 2, wn = wv & 3;

  int nwg = gridDim.x, bid = blockIdx.x;
  int s = (bid & 7) * (nwg >> 3) + (bid >> 3);  // XCD swizzle (nwg % 8 == 0 everywhere)
  int gm = M >> 8;
  int m0 = (s % gm) << 8, n0 = (s / gm) << 8;
  int nt = K >> 6;  // #K-tiles (BK=64); all uses have nt >= 8, nt even

  // ---- staging: per-thread source ptrs (pre-swizzled chunk: (ln&7)^(ln>>3)) ----
  const int r8 = ln >> 3, c8 = ln & 7;
  const int swz = (c8 ^ r8) * 8;
  const u16* pa[2]; const u16* pb[2];
#pragma unroll
  for (int i = 0; i < 2; i++) {
    pa[i] = A + (size_t)(m0 + i * 64 + wv * 8 + r8) * K + swz;
    pb[i] = Bt + (size_t)(n0 + i * 64 + wv * 8 + r8) * K + swz;
  }
  const int sb0 = wv * 512, sb1 = 4096 + wv * 512;  // wave-uniform LDS slots

  auto stage = [&](int mat, int h, int kt2) {
    int reg = (((kt2 & 1) * 2 + mat) * 2 + h) * 8192;
    const u16* g0 = (mat ? pb[0] : pa[0]) + (size_t)h * 128 * K + kt2 * 64;
    const u16* g1 = (mat ? pb[1] : pa[1]) + (size_t)h * 128 * K + kt2 * 64;
    async16(&lds[reg + sb0], g0);
    async16(&lds[reg + sb1], g1);
  };

  // ---- fragment read bases; read chunk (kk*4+hi)^(lo&7) undoes the pre-swizzle ----
  const int axor = lo & 7;
  const int cc0 = (hi ^ axor) * 8;
  const int cc1 = ((4 + hi) ^ axor) * 8;
  const u16* aB = &lds[wm * 8192 + lo * 64];
  const u16* bB = &lds[16384 + (wn >> 1) * 8192 + ((wn & 1) * 64 + lo) * 64];

  f4v acc[8][4] = {};

  // ---- prologue: k0 fully + k1 {B0,B1,A0}; vmcnt(6) => k0 complete ----
  stage(1, 0, 0); stage(1, 1, 0); stage(0, 0, 0); stage(0, 1, 0);
  stage(1, 0, 1); stage(1, 1, 1); stage(0, 0, 1);
  asm volatile("s_waitcnt vmcnt(6)" ::: "memory");
  __builtin_amdgcn_s_barrier();

  for (int kt = 0; kt < nt; ++kt) {
    const int db32 = (kt & 1) * 32768;
    s8v af[4][2], bf[4][2];
    // ---- P1: read af(mi0-3) + bf(all); stage A1(kt+1); MFMA m0q x n0q ----
#pragma unroll
    for (int mi = 0; mi < 4; mi++) {
      af[mi][0] = *(const s8v*)(aB + db32 + mi * 1024 + cc0);
      af[mi][1] = *(const s8v*)(aB + db32 + mi * 1024 + cc1);
    }
#pragma unroll
    for (int ni = 0; ni < 4; ni++) {
      bf[ni][0] = *(const s8v*)(bB + db32 + ni * 1024 + cc0);
      bf[ni][1] = *(const s8v*)(bB + db32 + ni * 1024 + cc1);
    }
    if (kt + 1 < nt) stage(0, 1, kt + 1);
    __builtin_amdgcn_s_barrier();
    __builtin_amdgcn_s_setprio(1);
#pragma unroll
    for (int mi = 0; mi < 4; mi++)
#pragma unroll
      for (int ni = 0; ni < 2; ni++)
#pragma unroll
        for (int kk = 0; kk < 2; kk++)
          acc[mi][ni] = __builtin_amdgcn_mfma_f32_16x16x32_bf16(af[mi][kk], bf[ni][kk], acc[mi][ni], 0, 0, 0);
    __builtin_amdgcn_s_setprio(0);
    __builtin_amdgcn_s_barrier();
    // ---- P2: stage B0(kt+2); MFMA m0q x n1q ----
    if (kt + 2 < nt) stage(1, 0, kt + 2);
    __builtin_amdgcn_s_barrier();
    __builtin_amdgcn_s_setprio(1);
#pragma unroll
    for (int mi = 0; mi < 4; mi++)
#pragma unroll
      for (int ni = 2; ni < 4; ni++)
#pragma unroll
        for (int kk = 0; kk < 2; kk++)
          acc[mi][ni] = __builtin_amdgcn_mfma_f32_16x16x32_bf16(af[mi][kk], bf[ni][kk], acc[mi][ni], 0, 0, 0);
    __builtin_amdgcn_s_setprio(0);
    __builtin_amdgcn_s_barrier();
    // ---- P3: read af(mi4-7); stage B1(kt+2); MFMA m1q x n1q ----
#pragma unroll
    for (int mi = 0; mi < 4; mi++) {
      af[mi][0] = *(const s8v*)(aB + db32 + (mi + 4) * 1024 + cc0);
      af[mi][1] = *(const s8v*)(aB + db32 + (mi + 4) * 1024 + cc1);
    }
    if (kt + 2 < nt) stage(1, 1, kt + 2);
    __builtin_amdgcn_s_barrier();
    __builtin_amdgcn_s_setprio(1);
#pragma unroll
    for (int mi = 0; mi < 4; mi++)
#pragma unroll
      for (int ni = 2; ni < 4; ni++)
#pragma unroll
        for (int kk = 0; kk < 2; kk++)
          acc[mi + 4][ni] = __builtin_amdgcn_mfma_f32_16x16x32_bf16(af[mi][kk], bf[ni][kk], acc[mi + 4][ni], 0, 0, 0);
    __builtin_amdgcn_s_setprio(0);
    __builtin_amdgcn_s_barrier();
    // ---- P4: stage A0(kt+2); vmcnt checkpoint; MFMA m1q x n0q ----
    if (kt + 2 < nt) {
      stage(0, 0, kt + 2);
      asm volatile("s_waitcnt vmcnt(6)" ::: "memory");
    } else {
      asm volatile("s_waitcnt vmcnt(0)" ::: "memory");
    }
    __builtin_amdgcn_s_barrier();
    __builtin_amdgcn_s_setprio(1);
#pragma unroll
    for (int mi = 0; mi < 4; mi++)
#pragma unroll
      for (int ni = 0; ni < 2; ni++)
#pragma unroll
        for (int kk = 0; kk < 2; kk++)
          acc[mi + 4][ni] = __builtin_amdgcn_mfma_f32_16x16x32_bf16(af[mi][kk], bf[ni][kk], acc[mi + 4][ni], 0, 0, 0);
    __builtin_amdgcn_s_setprio(0);
    __builtin_amdgcn_s_barrier();
  }

  // ---- epilogue ----
  bool second = (n0 >= split);  // block-uniform (splits are multiples of 256)
#pragma unroll
  for (int mi = 0; mi < 8; mi++)
#pragma unroll
    for (int ni = 0; ni < 4; ni++)
#pragma unroll
      for (int j = 0; j < 4; j++) {
        int row = m0 + wm * 128 + mi * 16 + hi * 4 + j;
        int col = n0 + wn * 64 + ni * 16 + lo;
        float v = acc[mi][ni][j];
        if constexpr (EPI == 1) {
          ((float*)C0v)[(size_t)row * N + col] = v;
        } else if constexpr (EPI == 2) {
          if (second) ((u16*)C1v)[(size_t)row * 512 + (col - 1536)] = f2bf(v);
          else        ((u16*)C0v)[(size_t)row * 1536 + col] = f2bf(v);
        } else if constexpr (EPI == 3) {
          if (second) ((u16*)C1v)[(size_t)row * 1024 + (col - 2048)] = f2bf(v);
          else        ((u16*)C0v)[(size_t)row * 3072 + (col >> 7) * 192 + (col & 127)] = f2bf(v);
        } else {  // EPI == 4
          if (second) ((u16*)C1v)[(size_t)row * 2048 + (col - 2048)] = f2bf(v);
          else        ((u16*)C0v)[(size_t)row * 3072 + (col >> 7) * 192 + (col & 127)] = f2bf(v);
        }
      }
}

// ---------------- small GEMM (m97 structure), kept for W_kr (N=64) ----------------
__global__ __launch_bounds__(256, 2) void k_gemm_kr(const u16* __restrict__ A,
                                                    const u16* __restrict__ Bt,
                                                    u16* __restrict__ C,
                                                    int M, int N, int K) {
  constexpr int BM = 128, BN = 64, FM = 2, FN = 4;  // 4 waves: 4M x 1N
  __shared__ __align__(16) u16 As[BM * 32];
  __shared__ __align__(16) u16 Bs[BN * 32];
  const int tid = threadIdx.x, wv = tid >> 6, ln = tid & 63;
  const int lo = ln & 15, hi = ln >> 4;
  int nwg = gridDim.x, bid = blockIdx.x;
  int sblk = (bid & 7) * (nwg >> 3) + (bid >> 3);
  int gm = M / BM;
  int m0 = (sblk % gm) * BM, n0 = (sblk / gm) * BN;
  f4v acc[FM][FN] = {};
  for (int k0 = 0; k0 < K; k0 += 32) {
    __syncthreads();
#pragma unroll
    for (int i = 0; i < BM / 64; i++) {
      int r = i * 64 + wv * 16 + (ln >> 2);
      async16(&As[(i * 64 + wv * 16) * 32], A + (size_t)(m0 + r) * K + k0 + (ln & 3) * 8);
    }
    {
      int r = wv * 16 + (ln >> 2);
      async16(&Bs[(wv * 16) * 32], Bt + (size_t)(n0 + r) * K + k0 + (ln & 3) * 8);
    }
    __syncthreads();
    s8v af[FM], bf[FN];
#pragma unroll
    for (int m = 0; m < FM; m++)
      af[m] = *(const s8v*)&As[(wv * FM * 16 + m * 16 + lo) * 32 + hi * 8];
#pragma unroll
    for (int n = 0; n < FN; n++)
      bf[n] = *(const s8v*)&Bs[(n * 16 + lo) * 32 + hi * 8];
#pragma unroll
    for (int m = 0; m < FM; m++)
#pragma unroll
      for (int n = 0; n < FN; n++)
        acc[m][n] = __builtin_amdgcn_mfma_f32_16x16x32_bf16(af[m], bf[n], acc[m][n], 0, 0, 0);
  }
#pragma unroll
  for (int m = 0; m < FM; m++)
#pragma unroll
    for (int n = 0; n < FN; n++)
#pragma unroll
      for (int j = 0; j < 4; j++) {
        int row = m0 + wv * FM * 16 + m * 16 + hi * 4 + j;
        int col = n0 + n * 16 + lo;
        C[(size_t)row * N + col] = f2bf(acc[m][n][j]);
      }
}

// ---------------- in-place RMSNorm over rows of bf16 (block = C/8 threads) ----------
__global__ void k_rmsnorm(u16* __restrict__ buf, const float* __restrict__ g, int C) {
  int row = blockIdx.x;
  u16* p = buf + (size_t)row * C;
  int tid = threadIdx.x;
  float x[8];
  float ss = 0.f;
  s8v v = *(const s8v*)(p + tid * 8);
#pragma unroll
  for (int i = 0; i < 8; i++) { float xi = bf2f((u16)v[i]); x[i] = xi; ss += xi * xi; }
#pragma unroll
  for (int off = 1; off < 64; off <<= 1) ss += __shfl_xor(ss, off);
  __shared__ float red[4];
  if (tid < 4) red[tid] = 0.f;
  __syncthreads();
  if ((tid & 63) == 0) red[tid >> 6] = ss;
  __syncthreads();
  float sc = rsqrtf((red[0] + red[1] + red[2] + red[3]) / (float)C + 1e-6f);
  s8v ov;
#pragma unroll
  for (int i = 0; i < 8; i++) ov[i] = (short)f2bf(x[i] * sc * g[tid * 8 + i]);
  *(s8v*)(p + tid * 8) = ov;
}

// ---------------- RoPE on q_rope, scatter into qbuf[:, h*192+128 ..] ----------------
__global__ __launch_bounds__(256) void k_rope_q(const u16* __restrict__ qr,
                                                const float* __restrict__ freqs,
                                                u16* __restrict__ qbuf) {
  int idx = blockIdx.x * 256 + threadIdx.x;  // (r,h)
  int r = idx >> 4, h = idx & 15;
  int t = r & 2047;
  const u16* src = qr + (size_t)r * 1024 + h * 64;
  u16* dst = qbuf + (size_t)r * 3072 + h * 192 + 128;
  const float* fc = freqs + (size_t)t * 64;
  u16 in[64], out[64];
#pragma unroll
  for (int c = 0; c < 8; c++) {
    s8v vv = *(const s8v*)(src + c * 8);
#pragma unroll
    for (int e = 0; e < 8; e++) in[c * 8 + e] = (u16)vv[e];
  }
#pragma unroll
  for (int i = 0; i < 32; i++) {
    float x1 = bf2f(in[2 * i]), x2 = bf2f(in[2 * i + 1]);
    float co = fc[2 * i], si = fc[2 * i + 1];
    out[2 * i] = f2bf(x1 * co - x2 * si);
    out[2 * i + 1] = f2bf(x1 * si + x2 * co);
  }
#pragma unroll
  for (int c = 0; c < 8; c++) {
    s8v ov;
#pragma unroll
    for (int e = 0; e < 8; e++) ov[e] = (short)out[c * 8 + e];
    *(s8v*)(dst + c * 8) = ov;
  }
}

// ---------------- RoPE on k_rope (shared across heads), broadcast into kbuf ----------
__global__ __launch_bounds__(256) void k_rope_k(const u16* __restrict__ kr,
                                                const float* __restrict__ freqs,
                                                u16* __restrict__ kbuf) {
  int idx = blockIdx.x * 256 + threadIdx.x;  // (r,h)
  int r = idx >> 4, h = idx & 15;
  int t = r & 2047;
  const u16* src = kr + (size_t)r * 64;
  u16* dst = kbuf + (size_t)r * 3072 + h * 192 + 128;
  const float* fc = freqs + (size_t)t * 64;
  u16 in[64], out[64];
#pragma unroll
  for (int c = 0; c < 8; c++) {
    s8v vv = *(const s8v*)(src + c * 8);
#pragma unroll
    for (int e = 0; e < 8; e++) in[c * 8 + e] = (u16)vv[e];
  }
#pragma unroll
  for (int i = 0; i < 32; i++) {
    float x1 = bf2f(in[2 * i]), x2 = bf2f(in[2 * i + 1]);
    float co = fc[2 * i], si = fc[2 * i + 1];
    out[2 * i] = f2bf(x1 * co - x2 * si);
    out[2 * i + 1] = f2bf(x1 * si + x2 * co);
  }
#pragma unroll
  for (int c = 0; c < 8; c++) {
    s8v ov;
#pragma unroll
    for (int e = 0; e < 8; e++) ov[e] = (short)out[c * 8 + e];
    *(s8v*)(dst + c * 8) = ov;
  }
}

// ---------------- V (token, h*128+d) -> Vt (B,H,128,T) ----------------
__global__ __launch_bounds__(256) void k_transpose_v(const u16* __restrict__ vtmp,
                                                     u16* __restrict__ vt) {
  __shared__ __align__(16) u16 tile[64][72];
  int r0 = blockIdx.x * 64, c0 = blockIdx.y * 64;
  int b = r0 >> 11, t0 = r0 & 2047;
  int h = c0 >> 7, d0 = c0 & 127;
  int tid = threadIdx.x;
  int ci = (tid & 7) * 8, ri = tid >> 3;
#pragma unroll
  for (int i = 0; i < 2; i++)
    *(s8v*)&tile[ri + 32 * i][ci] =
        *(const s8v*)(vtmp + (size_t)(r0 + ri + 32 * i) * 2048 + c0 + ci);
  __syncthreads();
  int tx = tid & 7, rr = tid >> 3;
#pragma unroll
  for (int i = 0; i < 2; i++) {
    int dr = rr + 32 * i;
    s8v ov;
#pragma unroll
    for (int e = 0; e < 8; e++) ov[e] = (short)tile[tx * 8 + e][dr];
    *(s8v*)(vt + (size_t)((b * 16 + h) * 128 + d0 + dr) * 2048 + t0 + tx * 8) = ov;
  }
}

// ---------------- causal flash attention, LDS-staged K/V ----------------
// (r3 structure, setprio REVERTED: m190 -- setprio hurts barrier-locked waves)
__global__ __launch_bounds__(256, 3) void k_attn(const u16* __restrict__ Q,
                                                 const u16* __restrict__ K,
                                                 const u16* __restrict__ V,
                                                 u16* __restrict__ O) {
  __shared__ __align__(16) u16 Ks[64 * 192];
  __shared__ __align__(16) u16 Vs[128 * 64];
  __shared__ __align__(16) u16 p_lds[4][16 * 88];
  int bid = blockIdx.x;
  int lw = (bid & 7) * 256 + (bid >> 3);
  int qt = 31 - (lw & 31), h = (lw >> 5) & 15, b = lw >> 9;
  int tid = threadIdx.x, wv = tid >> 6, ln = tid & 63;
  int lo = ln & 15, hi = ln >> 4, lo7 = lo & 7;
  int qb = qt * 64 + wv * 16;

  const u16* qptr = Q + (size_t)(b * 2048 + qb + lo) * 3072 + h * 192 + hi * 8;
  s8v qf[6];
#pragma unroll
  for (int ks = 0; ks < 6; ks++) qf[ks] = *(const s8v*)(qptr + ks * 32);

  f4v Oa[8] = {};
  float m_r[4], lpart[4];
#pragma unroll
  for (int j = 0; j < 4; j++) { m_r[j] = -3e38f; lpart[j] = 0.f; }
  const float sl2 = 0.07216878364870323f * 1.44269504f;  // scale * log2(e)
  const float THRU = 11.5f / sl2;

  const u16* kg = K + (size_t)(b * 2048) * 3072 + h * 192;
  const u16* vg = V + (size_t)((b * 16 + h) * 128) * 2048;
  int kgo[6], klo[6];
#pragma unroll
  for (int i = 0; i < 6; i++) {
    int id = i * 256 + tid, r = id / 24, c = id % 24;
    kgo[i] = r * 3072 + c * 8;
    klo[i] = r * 192 + (c ^ (r & 7)) * 8;
  }
  int vgo[4], vlo[4];
#pragma unroll
  for (int i = 0; i < 4; i++) {
    int id = i * 256 + tid, r = id >> 3, c = id & 7;
    vgo[i] = r * 2048 + c * 8;
    vlo[i] = r * 64 + (c ^ (r & 7)) * 8;
  }

  u16* pl = p_lds[wv];
  int last = (qb + 15) >> 6;
  s8v kreg[6], vreg[4];

#pragma unroll
  for (int i = 0; i < 6; i++) kreg[i] = *(const s8v*)(kg + kgo[i]);
#pragma unroll
  for (int i = 0; i < 4; i++) vreg[i] = *(const s8v*)(vg + vgo[i]);
#pragma unroll
  for (int i = 0; i < 6; i++) *(s8v*)&Ks[klo[i]] = kreg[i];
#pragma unroll
  for (int i = 0; i < 4; i++) *(s8v*)&Vs[vlo[i]] = vreg[i];
  __syncthreads();

  for (int t = 0; t <= last; t++) {
    int kv0 = t * 64;
    if (t < last) {
      size_t ksh = (size_t)(kv0 + 64) * 3072;
#pragma unroll
      for (int i = 0; i < 6; i++) kreg[i] = *(const s8v*)(kg + ksh + kgo[i]);
#pragma unroll
      for (int i = 0; i < 4; i++) vreg[i] = *(const s8v*)(vg + (kv0 + 64) + vgo[i]);
    }

    f4v S[4] = {};
#pragma unroll
    for (int ks = 0; ks < 6; ks++)
#pragma unroll
      for (int nf = 0; nf < 4; nf++) {
        s8v kf = *(const s8v*)&Ks[(nf * 16 + lo) * 192 + (((ks * 4 + hi) ^ lo7) * 8)];
        S[nf] = __builtin_amdgcn_mfma_f32_16x16x32_bf16(qf[ks], kf, S[nf], 0, 0, 0);
      }

    float p[4][4], tmax[4];
#pragma unroll
    for (int j = 0; j < 4; j++) tmax[j] = -3e38f;
    if (t == last) {
#pragma unroll
      for (int nf = 0; nf < 4; nf++)
#pragma unroll
        for (int j = 0; j < 4; j++) {
          float sv = S[nf][j];
          if (kv0 + nf * 16 + lo > qb + hi * 4 + j) sv = -3e38f;
          p[nf][j] = sv;
          tmax[j] = fmaxf(tmax[j], sv);
        }
    } else {
#pragma unroll
      for (int nf = 0; nf < 4; nf++)
#pragma unroll
        for (int j = 0; j < 4; j++) {
          p[nf][j] = S[nf][j];
          tmax[j] = fmaxf(tmax[j], S[nf][j]);
        }
    }
    bool need = false;
#pragma unroll
    for (int j = 0; j < 4; j++) need = need || (tmax[j] > m_r[j] + THRU);
    if (__any(need)) {
#pragma unroll
      for (int off = 1; off < 16; off <<= 1)
#pragma unroll
        for (int j = 0; j < 4; j++) tmax[j] = fmaxf(tmax[j], __shfl_xor(tmax[j], off));
#pragma unroll
      for (int j = 0; j < 4; j++) {
        float nm = fmaxf(m_r[j], tmax[j]);
        float fj = exp2f((m_r[j] - nm) * sl2);
        m_r[j] = nm;
        lpart[j] *= fj;
#pragma unroll
        for (int df = 0; df < 8; df++) Oa[df][j] *= fj;
      }
    }
#pragma unroll
    for (int nf = 0; nf < 4; nf++)
#pragma unroll
      for (int j = 0; j < 4; j++) {
        float pv = exp2f((p[nf][j] - m_r[j]) * sl2);
        p[nf][j] = pv;
        lpart[j] += pv;
      }

#pragma unroll
    for (int nf = 0; nf < 4; nf++)
#pragma unroll
      for (int j = 0; j < 4; j++)
        pl[(hi * 4 + j) * 88 + nf * 16 + lo] = f2bf(p[nf][j]);

#pragma unroll
    for (int ks2 = 0; ks2 < 2; ks2++) {
      s8v pa = *(const s8v*)&pl[lo * 88 + ks2 * 32 + hi * 8];
#pragma unroll
      for (int df = 0; df < 8; df++) {
        s8v vf = *(const s8v*)&Vs[(df * 16 + lo) * 64 + (((ks2 * 4 + hi) ^ lo7) * 8)];
        Oa[df] = __builtin_amdgcn_mfma_f32_16x16x32_bf16(pa, vf, Oa[df], 0, 0, 0);
      }
    }

    __syncthreads();
    if (t < last) {
#pragma unroll
      for (int i = 0; i < 6; i++) *(s8v*)&Ks[klo[i]] = kreg[i];
#pragma unroll
      for (int i = 0; i < 4; i++) *(s8v*)&Vs[vlo[i]] = vreg[i];
      __syncthreads();
    }
  }

#pragma unroll
  for (int off = 1; off < 16; off <<= 1)
#pragma unroll
    for (int j = 0; j < 4; j++) lpart[j] += __shfl_xor(lpart[j], off);

#pragma unroll
  for (int j = 0; j < 4; j++) {
    float inv = 1.0f / lpart[j];
    u16* orow = O + (size_t)(b * 2048 + qb + hi * 4 + j) * 2048 + h * 128;
#pragma unroll
    for (int df = 0; df < 8; df++) orow[df * 16 + lo] = f2bf(Oa[df][j] * inv);
  }
}

// =====================================================================
extern "C" void kernel_launch(void* const* d_in, const int* in_sizes, int n_in,
                              void* d_out, int out_size, void* d_ws, size_t ws_size,
                              hipStream_t stream) {
  (void)in_sizes; (void)n_in; (void)out_size; (void)ws_size;
  const float* x     = (const float*)d_in[0];
  const float* freqs = (const float*)d_in[2];
  const float* W_dq  = (const float*)d_in[4];
  const float* W_uq  = (const float*)d_in[5];
  const float* W_dkv = (const float*)d_in[6];
  const float* W_uk  = (const float*)d_in[7];
  const float* W_uv  = (const float*)d_in[8];
  const float* W_qr  = (const float*)d_in[9];
  const float* W_kr  = (const float*)d_in[10];
  const float* W_o   = (const float*)d_in[11];
  const float* g_q   = (const float*)d_in[12];
  const float* g_kv  = (const float*)d_in[13];
  float* out = (float*)d_out;

  const int M = 8192;  // B*T
  char* w = (char*)d_ws;
  auto alloc = [&](size_t n) { char* p = w; w += (n + 255) & ~(size_t)255; return p; };

  u16* xb     = (u16*)alloc((size_t)M * 2048 * 2);  // reused as vtmp and aout
  // fused-B pairs MUST stay contiguous:
  u16* wdq    = (u16*)alloc((size_t)1536 * 2048 * 2);
  u16* wdkv   = (u16*)alloc((size_t)512 * 2048 * 2);
  u16* wuq    = (u16*)alloc((size_t)2048 * 1536 * 2);
  u16* wqr    = (u16*)alloc((size_t)1024 * 1536 * 2);
  u16* wuk    = (u16*)alloc((size_t)2048 * 512 * 2);
  u16* wuv    = (u16*)alloc((size_t)2048 * 512 * 2);
  u16* wkr    = (u16*)alloc((size_t)64 * 2048 * 2);
  u16* wo     = (u16*)alloc((size_t)2048 * 2048 * 2);
  u16* q_c    = (u16*)alloc((size_t)M * 1536 * 2);
  u16* kv_c   = (u16*)alloc((size_t)M * 512 * 2);
  u16* qr_raw = (u16*)alloc((size_t)M * 1024 * 2);
  u16* kr_raw = (u16*)alloc((size_t)M * 64 * 2);
  u16* qbuf   = (u16*)alloc((size_t)M * 3072 * 2);
  u16* kbuf   = (u16*)alloc((size_t)M * 3072 * 2);
  u16* vt     = (u16*)alloc((size_t)M * 2048 * 2);
  u16* vtmp = xb;  // xb dead after kr GEMM
  u16* aout = xb;

  // ---- preamble ----
  k_f32_to_bf16<<<M * 2048 / 8 / 256, 256, 0, stream>>>(x, xb, M * 2048 / 8);
  k_transpose_all<<<14976, 256, 0, stream>>>(W_dq, W_dkv, W_uq, W_qr, W_uk, W_uv, W_kr, W_o,
                                             wdq, wdkv, wuq, wqr, wuk, wuv, wkr, wo);

  // ---- fused latent projections (dq|dkv) + RMSNorm ----
  k_gemm8<2><<<(M / 256) * (2048 / 256), 512, 0, stream>>>(
      xb, wdq, q_c, kv_c, M, 2048, 2048, 1536);
  k_rmsnorm<<<M, 192, 0, stream>>>(q_c, g_q, 1536);
  k_rmsnorm<<<M, 64, 0, stream>>>(kv_c, g_kv, 512);

  // ---- fused Q up-projections (uq|qr) + rope ----
  k_gemm8<3><<<(M / 256) * (3072 / 256), 512, 0, stream>>>(
      q_c, wuq, qbuf, qr_raw, M, 3072, 1536, 2048);
  k_rope_q<<<M * 16 / 256, 256, 0, stream>>>(qr_raw, freqs, qbuf);

  // ---- K rope path (reads xb -> must precede ukuv which writes vtmp=xb) ----
  k_gemm_kr<<<(M / 128) * (64 / 64), 256, 0, stream>>>(xb, wkr, kr_raw, M, 64, 2048);
  k_rope_k<<<M * 16 / 256, 256, 0, stream>>>(kr_raw, freqs, kbuf);

  // ---- fused KV up-projections (uk|uv) + V transpose ----
  k_gemm8<4><<<(M / 256) * (4096 / 256), 512, 0, stream>>>(
      kv_c, wuk, kbuf, vtmp, M, 4096, 512, 2048);
  k_transpose_v<<<dim3(M / 64, 2048 / 64), 256, 0, stream>>>(vtmp, vt);

  // ---- attention ----
  k_attn<<<4 * 16 * 32, 256, 0, stream>>>(qbuf, kbuf, vt, aout);

  // ---- output projection (f32 out) ----
  k_gemm8<1><<<(M / 256) * (2048 / 256), 512, 0, stream>>>(
      aout, wo, out, nullptr, M, 2048, 2048, 1 << 30);
}